// Round 3
// baseline (690.379 us; speedup 1.0000x reference)
//
#include <hip/hip_runtime.h>
#include <math.h>

#define DD 16384
#define NQ 14

__device__ __forceinline__ void atomAddF(float* p, float v) {
#if defined(__HIP_PLATFORM_AMD__)
    unsafeAtomicAdd(p, v);   // HW global_atomic_add_f32 (values are normal-range)
#else
    atomicAdd(p, v);
#endif
}

// ---------------- norm: sum of squares over 16384 re/im pairs ----------------
__global__ __launch_bounds__(256) void k_norm(const float4* __restrict__ qr4,
                                              const float4* __restrict__ qi4,
                                              float* __restrict__ sum) {
    __shared__ float sred[4];
    int t = blockIdx.x * 256 + threadIdx.x;
    float4 r = qr4[t], m = qi4[t];
    float v = r.x * r.x + r.y * r.y + r.z * r.z + r.w * r.w +
              m.x * m.x + m.y * m.y + m.z * m.z + m.w * m.w;
#pragma unroll
    for (int off = 32; off; off >>= 1) v += __shfl_down(v, off);
    if ((threadIdx.x & 63) == 0) sred[threadIdx.x >> 6] = v;
    __syncthreads();
    if (threadIdx.x == 0) atomAddF(sum, sred[0] + sred[1] + sred[2] + sred[3]);
}

// ---------------- prep: re/im normalized (x = [re||im]) and phases ----------------
__global__ __launch_bounds__(256) void k_prep(const float4* __restrict__ qr4,
                                              const float4* __restrict__ qi4,
                                              const float* __restrict__ sum,
                                              float4* __restrict__ x4,
                                              float4* __restrict__ ph4) {
    int t = blockIdx.x * 256 + threadIdx.x;
    float inv = 1.0f / sqrtf(*sum);
    float4 r = qr4[t], m = qi4[t];
    float4 xr = {r.x * inv, r.y * inv, r.z * inv, r.w * inv};
    float4 xi = {m.x * inv, m.y * inv, m.z * inv, m.w * inv};
    x4[t] = xr;
    x4[DD / 4 + t] = xi;
    float4 p = {atan2f(m.x, r.x), atan2f(m.y, r.y), atan2f(m.z, r.z), atan2f(m.w, r.w)};
    ph4[t] = p;
}

// ---------------- generic matvec: acc[c] += sum_i act(x[i]) * W[i*C + c] ----------------
// block = C/4 threads, each thread owns one float4 (4 consecutive columns).
// grid.x = R / rpc chunks. chunk 0 folds obias. act: 0 = identity, 1 = relu(x + xbias).
__global__ __launch_bounds__(512, 4) void k_matvec(const float* __restrict__ W,
                                                   const float* __restrict__ xpre,
                                                   const float* __restrict__ xbias, int act,
                                                   float* __restrict__ acc,
                                                   const float* __restrict__ obias,
                                                   int C4, int R, int rpc) {
    __shared__ float sx[128];
    int chunk = blockIdx.x;
    int r0 = chunk * rpc;
    int nr = min(rpc, R - r0);
    for (int i = threadIdx.x; i < nr; i += blockDim.x) {
        float v = xpre[r0 + i];
        if (act) v = fmaxf(v + xbias[r0 + i], 0.0f);
        sx[i] = v;
    }
    __syncthreads();
    const float4* __restrict__ Wp =
        reinterpret_cast<const float4*>(W) + (size_t)r0 * C4 + threadIdx.x;
    // two independent accumulator streams (even/odd unrolled rows)
    float ax = 0.f, ay = 0.f, az = 0.f, aw = 0.f;
    float bx = 0.f, by = 0.f, bz = 0.f, bw = 0.f;
    int i = 0;
    for (; i + 8 <= nr; i += 8) {
        float4 w0 = Wp[0];
        float4 w1 = Wp[(size_t)C4 * 1];
        float4 w2 = Wp[(size_t)C4 * 2];
        float4 w3 = Wp[(size_t)C4 * 3];
        float4 w4 = Wp[(size_t)C4 * 4];
        float4 w5 = Wp[(size_t)C4 * 5];
        float4 w6 = Wp[(size_t)C4 * 6];
        float4 w7 = Wp[(size_t)C4 * 7];
        float x0 = sx[i + 0], x1 = sx[i + 1], x2 = sx[i + 2], x3 = sx[i + 3];
        float x4 = sx[i + 4], x5 = sx[i + 5], x6 = sx[i + 6], x7 = sx[i + 7];
        ax = fmaf(x0, w0.x, ax); ay = fmaf(x0, w0.y, ay); az = fmaf(x0, w0.z, az); aw = fmaf(x0, w0.w, aw);
        bx = fmaf(x1, w1.x, bx); by = fmaf(x1, w1.y, by); bz = fmaf(x1, w1.z, bz); bw = fmaf(x1, w1.w, bw);
        ax = fmaf(x2, w2.x, ax); ay = fmaf(x2, w2.y, ay); az = fmaf(x2, w2.z, az); aw = fmaf(x2, w2.w, aw);
        bx = fmaf(x3, w3.x, bx); by = fmaf(x3, w3.y, by); bz = fmaf(x3, w3.z, bz); bw = fmaf(x3, w3.w, bw);
        ax = fmaf(x4, w4.x, ax); ay = fmaf(x4, w4.y, ay); az = fmaf(x4, w4.z, az); aw = fmaf(x4, w4.w, aw);
        bx = fmaf(x5, w5.x, bx); by = fmaf(x5, w5.y, by); bz = fmaf(x5, w5.z, bz); bw = fmaf(x5, w5.w, bw);
        ax = fmaf(x6, w6.x, ax); ay = fmaf(x6, w6.y, ay); az = fmaf(x6, w6.z, az); aw = fmaf(x6, w6.w, aw);
        bx = fmaf(x7, w7.x, bx); by = fmaf(x7, w7.y, by); bz = fmaf(x7, w7.z, bz); bw = fmaf(x7, w7.w, bw);
        Wp += (size_t)C4 * 8;
    }
    for (; i < nr; i++) {
        float4 w = *Wp;
        Wp += C4;
        float xv = sx[i];
        ax = fmaf(xv, w.x, ax); ay = fmaf(xv, w.y, ay);
        az = fmaf(xv, w.z, az); aw = fmaf(xv, w.w, aw);
    }
    ax += bx; ay += by; az += bz; aw += bw;
    int col = threadIdx.x * 4;
    if (chunk == 0 && obias) {
        ax += obias[col + 0]; ay += obias[col + 1];
        az += obias[col + 2]; aw += obias[col + 3];
    }
    atomAddF(&acc[col + 0], ax);
    atomAddF(&acc[col + 1], ay);
    atomAddF(&acc[col + 2], az);
    atomAddF(&acc[col + 3], aw);
}

// ---------------- layernorm over 2048 (adds b2 first), one block of 512 ----------------
__global__ __launch_bounds__(512) void k_ln(const float* __restrict__ a,
                                            const float* __restrict__ b2,
                                            const float* __restrict__ g,
                                            const float* __restrict__ bb,
                                            float* __restrict__ out) {
    __shared__ float s1[8], s2[8];
    int tid = threadIdx.x;
    float v[4];
    float s = 0.f;
#pragma unroll
    for (int e = 0; e < 4; e++) {
        int idx = tid + 512 * e;
        v[e] = a[idx] + b2[idx];
        s += v[e];
    }
#pragma unroll
    for (int off = 32; off; off >>= 1) s += __shfl_down(s, off);
    if ((tid & 63) == 0) s1[tid >> 6] = s;
    __syncthreads();
    float tot = s1[0] + s1[1] + s1[2] + s1[3] + s1[4] + s1[5] + s1[6] + s1[7];
    float mean = tot * (1.0f / 2048.0f);
    float q = 0.f;
#pragma unroll
    for (int e = 0; e < 4; e++) {
        float d = v[e] - mean;
        q += d * d;
    }
#pragma unroll
    for (int off = 32; off; off >>= 1) q += __shfl_down(q, off);
    if ((tid & 63) == 0) s2[tid >> 6] = q;
    __syncthreads();
    float tv = s2[0] + s2[1] + s2[2] + s2[3] + s2[4] + s2[5] + s2[6] + s2[7];
    float var = tv * (1.0f / 2048.0f);
    float inv = 1.0f / sqrtf(var + 1e-5f);
#pragma unroll
    for (int e = 0; e < 4; e++) {
        int idx = tid + 512 * e;
        out[idx] = (v[e] - mean) * inv * g[idx] + bb[idx];
    }
}

// ---------------- entanglement path: 91 features + 91x512 MLP + 512x512 MLP ----------------
// single block of 512 threads (8 waves). x = [re||im] normalized.
__global__ __launch_bounds__(512) void k_ent(const float* __restrict__ x,
                                             const float* __restrict__ w1,
                                             const float* __restrict__ b1,
                                             const float* __restrict__ w2,
                                             const float* __restrict__ b2,
                                             float* __restrict__ out) {
    __shared__ float s_ef[96];
    __shared__ float s_h[512];
    int tid = threadIdx.x;
    int wave = tid >> 6, lane = tid & 63;
    const float* re = x;
    const float* im = x + DD;
    for (int p = wave; p < 91; p += 8) {
        // decode (i, j) from flat pair index p (i outer, j = i+1..13 inner)
        int i = 0, rem = p;
        while (rem >= (NQ - 1) - i) { rem -= (NQ - 1) - i; i++; }
        int j = i + 1 + rem;
        int si = 1 << (NQ - i - 1);
        int sj = 1 << (NQ - j - 1);
        int L = 1 << (i + 1);
        float rr = 0.f, ii = 0.f;
        for (int k = lane; k < L; k += 64) {
            float a = re[k * si], b = im[k * si];
            float c = re[1 + k * sj], d = im[1 + k * sj];
            rr += a * c - b * d;
            ii += a * d + b * c;
        }
#pragma unroll
        for (int off = 32; off; off >>= 1) {
            rr += __shfl_down(rr, off);
            ii += __shfl_down(ii, off);
        }
        if (lane == 0) s_ef[p] = sqrtf(rr * rr + ii * ii);
    }
    __syncthreads();
    // ent layer 1: h[t] = relu(sum_p ef[p] * w1[p*512 + t] + b1[t])
    float h = b1[tid];
    for (int p = 0; p < 91; p++) h = fmaf(s_ef[p], w1[p * 512 + tid], h);
    s_h[tid] = fmaxf(h, 0.f);
    __syncthreads();
    // ent layer 2: out[t] = sum_k h[k] * w2[k*512 + t] + b2[t]
    float o = b2[tid];
    for (int k = 0; k < 512; k++) o = fmaf(s_h[k], w2[k * 512 + tid], o);
    out[tid] = o;
}

extern "C" void kernel_launch(void* const* d_in, const int* in_sizes, int n_in,
                              void* d_out, int out_size, void* d_ws, size_t ws_size,
                              hipStream_t stream) {
    const float* qs_real = (const float*)d_in[0];
    const float* qs_imag = (const float*)d_in[1];
    const float* amp_w1  = (const float*)d_in[2];
    const float* amp_b1  = (const float*)d_in[3];
    const float* amp_w2  = (const float*)d_in[4];
    const float* amp_b2  = (const float*)d_in[5];
    const float* ln_g    = (const float*)d_in[6];
    const float* ln_b    = (const float*)d_in[7];
    const float* ph_w1   = (const float*)d_in[8];
    const float* ph_b1   = (const float*)d_in[9];
    const float* ph_w2   = (const float*)d_in[10];
    const float* ph_b2   = (const float*)d_in[11];
    const float* ent_w1  = (const float*)d_in[12];
    const float* ent_b1  = (const float*)d_in[13];
    const float* ent_w2  = (const float*)d_in[14];
    const float* ent_b2  = (const float*)d_in[15];
    const float* fus_w   = (const float*)d_in[16];
    const float* fus_b   = (const float*)d_in[17];
    float* out = (float*)d_out;
    float* ws = (float*)d_ws;

    // ws layout (float offsets)
    const int o_sum  = 0;       // 1      (zeroed)
    const int o_h1   = 1024;    // 2048   amp layer-1 acc (zeroed)
    const int o_a    = 4096;    // 2048   amp layer-2 acc (zeroed)
    const int o_p1   = 8192;    // 1024   phase layer-1 acc (zeroed)
    const int o_comb = 16384;   // 3584   [amp_emb | ph_emb(acc) | ent_emb] (zeroed)
    const int o_x    = 20480;   // 32768  re||im normalized
    const int o_ph   = 53248;   // 16384  phases

    // zero all accumulator regions + d_out (both re-poisoned before each call)
    hipMemsetAsync(d_ws, 0, (size_t)(o_comb + 3584) * sizeof(float), stream);
    hipMemsetAsync(d_out, 0, 2048 * sizeof(float), stream);

    k_norm<<<16, 256, 0, stream>>>((const float4*)qs_real, (const float4*)qs_imag, ws + o_sum);
    k_prep<<<16, 256, 0, stream>>>((const float4*)qs_real, (const float4*)qs_imag,
                                   ws + o_sum, (float4*)(ws + o_x), (float4*)(ws + o_ph));

    // amp path: x(32768) @ amp_w1(32768x2048) -> relu -> @ amp_w2(2048x2048) -> LN
    k_matvec<<<256, 512, 0, stream>>>(amp_w1, ws + o_x, nullptr, 0, ws + o_h1, nullptr,
                                      512, 2 * DD, 128);
    k_matvec<<<256, 512, 0, stream>>>(amp_w2, ws + o_h1, amp_b1, 1, ws + o_a, nullptr,
                                      512, 2048, 8);
    k_ln<<<1, 512, 0, stream>>>(ws + o_a, amp_b2, ln_g, ln_b, ws + o_comb);

    // phase path: phases(16384) @ ph_w1(16384x1024) -> relu -> @ ph_w2(1024x1024) + b2
    k_matvec<<<512, 256, 0, stream>>>(ph_w1, ws + o_ph, nullptr, 0, ws + o_p1, nullptr,
                                      256, DD, 32);
    k_matvec<<<256, 256, 0, stream>>>(ph_w2, ws + o_p1, ph_b1, 1, ws + o_comb + 2048, ph_b2,
                                      256, 1024, 4);

    // entanglement path (single block)
    k_ent<<<1, 512, 0, stream>>>(ws + o_x, ent_w1, ent_b1, ent_w2, ent_b2,
                                 ws + o_comb + 3072);

    // fusion: combined(3584) @ fus_w(3584x2048) + fus_b -> out
    k_matvec<<<256, 512, 0, stream>>>(fus_w, ws + o_comb, nullptr, 0, out, fus_b,
                                      512, 3584, 14);
}

// Round 5
// 637.588 us; speedup vs baseline: 1.0828x; 1.0828x over previous
//
#include <hip/hip_runtime.h>
#include <math.h>

#define DD 16384
#define NQ 14

__device__ __forceinline__ void atomAddF(float* p, float v) {
#if defined(__HIP_PLATFORM_AMD__)
    unsafeAtomicAdd(p, v);   // HW global_atomic_add_f32 (values are normal-range)
#else
    atomicAdd(p, v);
#endif
}

// ---------------- norm: sum of squares over 16384 re/im pairs ----------------
__global__ __launch_bounds__(256) void k_norm(const float4* __restrict__ qr4,
                                              const float4* __restrict__ qi4,
                                              float* __restrict__ sum) {
    __shared__ float sred[4];
    int t = blockIdx.x * 256 + threadIdx.x;
    float4 r = qr4[t], m = qi4[t];
    float v = r.x * r.x + r.y * r.y + r.z * r.z + r.w * r.w +
              m.x * m.x + m.y * m.y + m.z * m.z + m.w * m.w;
#pragma unroll
    for (int off = 32; off; off >>= 1) v += __shfl_down(v, off);
    if ((threadIdx.x & 63) == 0) sred[threadIdx.x >> 6] = v;
    __syncthreads();
    if (threadIdx.x == 0) atomAddF(sum, sred[0] + sred[1] + sred[2] + sred[3]);
}

// ---------------- prep: re/im normalized (x = [re||im]) and phases ----------------
__global__ __launch_bounds__(256) void k_prep(const float4* __restrict__ qr4,
                                              const float4* __restrict__ qi4,
                                              const float* __restrict__ sum,
                                              float4* __restrict__ x4,
                                              float4* __restrict__ ph4) {
    int t = blockIdx.x * 256 + threadIdx.x;
    float inv = 1.0f / sqrtf(*sum);
    float4 r = qr4[t], m = qi4[t];
    float4 xr = {r.x * inv, r.y * inv, r.z * inv, r.w * inv};
    float4 xi = {m.x * inv, m.y * inv, m.z * inv, m.w * inv};
    x4[t] = xr;
    x4[DD / 4 + t] = xi;
    float4 p = {atan2f(m.x, r.x), atan2f(m.y, r.y), atan2f(m.z, r.z), atan2f(m.w, r.w)};
    ph4[t] = p;
}

// ---------------- generic matvec: acc[c] += sum_i act(x[i]) * W[i*C + c] ----------------
// block = C/4 threads, each thread owns one float4 (4 consecutive columns).
// grid.x = R / rpc chunks. chunk 0 folds obias. act: 0 = identity, 1 = relu(x + xbias).
__global__ __launch_bounds__(512, 4) void k_matvec(const float* __restrict__ W,
                                                   const float* __restrict__ xpre,
                                                   const float* __restrict__ xbias, int act,
                                                   float* __restrict__ acc,
                                                   const float* __restrict__ obias,
                                                   int C4, int R, int rpc) {
    __shared__ float sx[128];
    int chunk = blockIdx.x;
    int r0 = chunk * rpc;
    int nr = min(rpc, R - r0);
    for (int i = threadIdx.x; i < nr; i += blockDim.x) {
        float v = xpre[r0 + i];
        if (act) v = fmaxf(v + xbias[r0 + i], 0.0f);
        sx[i] = v;
    }
    __syncthreads();
    const float4* __restrict__ Wp =
        reinterpret_cast<const float4*>(W) + (size_t)r0 * C4 + threadIdx.x;
    // two independent accumulator streams (even/odd unrolled rows)
    float ax = 0.f, ay = 0.f, az = 0.f, aw = 0.f;
    float bx = 0.f, by = 0.f, bz = 0.f, bw = 0.f;
    int i = 0;
    for (; i + 8 <= nr; i += 8) {
        float4 w0 = Wp[0];
        float4 w1 = Wp[(size_t)C4 * 1];
        float4 w2 = Wp[(size_t)C4 * 2];
        float4 w3 = Wp[(size_t)C4 * 3];
        float4 w4 = Wp[(size_t)C4 * 4];
        float4 w5 = Wp[(size_t)C4 * 5];
        float4 w6 = Wp[(size_t)C4 * 6];
        float4 w7 = Wp[(size_t)C4 * 7];
        float x0 = sx[i + 0], x1 = sx[i + 1], x2 = sx[i + 2], x3 = sx[i + 3];
        float x4 = sx[i + 4], x5 = sx[i + 5], x6 = sx[i + 6], x7 = sx[i + 7];
        ax = fmaf(x0, w0.x, ax); ay = fmaf(x0, w0.y, ay); az = fmaf(x0, w0.z, az); aw = fmaf(x0, w0.w, aw);
        bx = fmaf(x1, w1.x, bx); by = fmaf(x1, w1.y, by); bz = fmaf(x1, w1.z, bz); bw = fmaf(x1, w1.w, bw);
        ax = fmaf(x2, w2.x, ax); ay = fmaf(x2, w2.y, ay); az = fmaf(x2, w2.z, az); aw = fmaf(x2, w2.w, aw);
        bx = fmaf(x3, w3.x, bx); by = fmaf(x3, w3.y, by); bz = fmaf(x3, w3.z, bz); bw = fmaf(x3, w3.w, bw);
        ax = fmaf(x4, w4.x, ax); ay = fmaf(x4, w4.y, ay); az = fmaf(x4, w4.z, az); aw = fmaf(x4, w4.w, aw);
        bx = fmaf(x5, w5.x, bx); by = fmaf(x5, w5.y, by); bz = fmaf(x5, w5.z, bz); bw = fmaf(x5, w5.w, bw);
        ax = fmaf(x6, w6.x, ax); ay = fmaf(x6, w6.y, ay); az = fmaf(x6, w6.z, az); aw = fmaf(x6, w6.w, aw);
        bx = fmaf(x7, w7.x, bx); by = fmaf(x7, w7.y, by); bz = fmaf(x7, w7.z, bz); bw = fmaf(x7, w7.w, bw);
        Wp += (size_t)C4 * 8;
    }
    for (; i < nr; i++) {
        float4 w = *Wp;
        Wp += C4;
        float xv = sx[i];
        ax = fmaf(xv, w.x, ax); ay = fmaf(xv, w.y, ay);
        az = fmaf(xv, w.z, az); aw = fmaf(xv, w.w, aw);
    }
    ax += bx; ay += by; az += bz; aw += bw;
    int col = threadIdx.x * 4;
    if (chunk == 0 && obias) {
        ax += obias[col + 0]; ay += obias[col + 1];
        az += obias[col + 2]; aw += obias[col + 3];
    }
    atomAddF(&acc[col + 0], ax);
    atomAddF(&acc[col + 1], ay);
    atomAddF(&acc[col + 2], az);
    atomAddF(&acc[col + 3], aw);
}

// ---------------- layernorm over 2048 (adds b2 first), one block of 512 ----------------
__global__ __launch_bounds__(512) void k_ln(const float* __restrict__ a,
                                            const float* __restrict__ b2,
                                            const float* __restrict__ g,
                                            const float* __restrict__ bb,
                                            float* __restrict__ out) {
    __shared__ float s1[8], s2[8];
    int tid = threadIdx.x;
    float v[4];
    float s = 0.f;
#pragma unroll
    for (int e = 0; e < 4; e++) {
        int idx = tid + 512 * e;
        v[e] = a[idx] + b2[idx];
        s += v[e];
    }
#pragma unroll
    for (int off = 32; off; off >>= 1) s += __shfl_down(s, off);
    if ((tid & 63) == 0) s1[tid >> 6] = s;
    __syncthreads();
    float tot = s1[0] + s1[1] + s1[2] + s1[3] + s1[4] + s1[5] + s1[6] + s1[7];
    float mean = tot * (1.0f / 2048.0f);
    float q = 0.f;
#pragma unroll
    for (int e = 0; e < 4; e++) {
        float d = v[e] - mean;
        q += d * d;
    }
#pragma unroll
    for (int off = 32; off; off >>= 1) q += __shfl_down(q, off);
    if ((tid & 63) == 0) s2[tid >> 6] = q;
    __syncthreads();
    float tv = s2[0] + s2[1] + s2[2] + s2[3] + s2[4] + s2[5] + s2[6] + s2[7];
    float var = tv * (1.0f / 2048.0f);
    float inv = 1.0f / sqrtf(var + 1e-5f);
#pragma unroll
    for (int e = 0; e < 4; e++) {
        int idx = tid + 512 * e;
        out[idx] = (v[e] - mean) * inv * g[idx] + bb[idx];
    }
}

// ---------------- entanglement features: one block per pair p ----------------
// x = [re||im] normalized (L2-resident, 128 KB). 91 blocks x 256 threads.
__global__ __launch_bounds__(256) void k_efeat(const float* __restrict__ x,
                                               float* __restrict__ ef) {
    __shared__ float srr[4], sii[4];
    int p = blockIdx.x;
    // decode (i, j) from flat pair index p (i outer, j = i+1..13 inner)
    int i = 0, rem = p;
    while (rem >= (NQ - 1) - i) { rem -= (NQ - 1) - i; i++; }
    int j = i + 1 + rem;
    int si = 1 << (NQ - i - 1);
    int sj = 1 << (NQ - j - 1);
    int L = 1 << (i + 1);
    const float* re = x;
    const float* im = x + DD;
    float rr = 0.f, ii = 0.f;
    for (int k = threadIdx.x; k < L; k += 256) {
        float a = re[k * si], b = im[k * si];
        float c = re[1 + k * sj], d = im[1 + k * sj];
        rr += a * c - b * d;
        ii += a * d + b * c;
    }
#pragma unroll
    for (int off = 32; off; off >>= 1) {
        rr += __shfl_down(rr, off);
        ii += __shfl_down(ii, off);
    }
    if ((threadIdx.x & 63) == 0) {
        srr[threadIdx.x >> 6] = rr;
        sii[threadIdx.x >> 6] = ii;
    }
    __syncthreads();
    if (threadIdx.x == 0) {
        float R = srr[0] + srr[1] + srr[2] + srr[3];
        float I = sii[0] + sii[1] + sii[2] + sii[3];
        ef[p] = sqrtf(R * R + I * I);
    }
}

extern "C" void kernel_launch(void* const* d_in, const int* in_sizes, int n_in,
                              void* d_out, int out_size, void* d_ws, size_t ws_size,
                              hipStream_t stream) {
    const float* qs_real = (const float*)d_in[0];
    const float* qs_imag = (const float*)d_in[1];
    const float* amp_w1  = (const float*)d_in[2];
    const float* amp_b1  = (const float*)d_in[3];
    const float* amp_w2  = (const float*)d_in[4];
    const float* amp_b2  = (const float*)d_in[5];
    const float* ln_g    = (const float*)d_in[6];
    const float* ln_b    = (const float*)d_in[7];
    const float* ph_w1   = (const float*)d_in[8];
    const float* ph_b1   = (const float*)d_in[9];
    const float* ph_w2   = (const float*)d_in[10];
    const float* ph_b2   = (const float*)d_in[11];
    const float* ent_w1  = (const float*)d_in[12];
    const float* ent_b1  = (const float*)d_in[13];
    const float* ent_w2  = (const float*)d_in[14];
    const float* ent_b2  = (const float*)d_in[15];
    const float* fus_w   = (const float*)d_in[16];
    const float* fus_b   = (const float*)d_in[17];
    float* out = (float*)d_out;
    float* ws = (float*)d_ws;

    // ws layout (float offsets)
    const int o_sum  = 0;       // 1      (zeroed)
    const int o_h1   = 1024;    // 2048   amp layer-1 acc (zeroed)
    const int o_a    = 4096;    // 2048   amp layer-2 acc (zeroed)
    const int o_p1   = 8192;    // 1024   phase layer-1 acc (zeroed)
    const int o_ef   = 12288;   // 91     ent features (zeroed)
    const int o_eh1  = 13312;   // 512    ent layer-1 acc (zeroed)
    const int o_comb = 16384;   // 3584   [amp_emb | ph_emb(acc) | ent_emb(acc)] (zeroed)
    const int o_x    = 20480;   // 32768  re||im normalized
    const int o_ph   = 53248;   // 16384  phases

    // zero all accumulator regions + d_out (both re-poisoned before each call)
    hipMemsetAsync(d_ws, 0, (size_t)(o_comb + 3584) * sizeof(float), stream);
    hipMemsetAsync(d_out, 0, 2048 * sizeof(float), stream);

    k_norm<<<16, 256, 0, stream>>>((const float4*)qs_real, (const float4*)qs_imag, ws + o_sum);
    k_prep<<<16, 256, 0, stream>>>((const float4*)qs_real, (const float4*)qs_imag,
                                   ws + o_sum, (float4*)(ws + o_x), (float4*)(ws + o_ph));

    // amp path: x(32768) @ amp_w1(32768x2048) -> relu -> @ amp_w2(2048x2048) -> LN
    k_matvec<<<256, 512, 0, stream>>>(amp_w1, ws + o_x, nullptr, 0, ws + o_h1, nullptr,
                                      512, 2 * DD, 128);
    k_matvec<<<256, 512, 0, stream>>>(amp_w2, ws + o_h1, amp_b1, 1, ws + o_a, nullptr,
                                      512, 2048, 8);
    k_ln<<<1, 512, 0, stream>>>(ws + o_a, amp_b2, ln_g, ln_b, ws + o_comb);

    // phase path: phases(16384) @ ph_w1(16384x1024) -> relu -> @ ph_w2(1024x1024) + b2
    k_matvec<<<512, 256, 0, stream>>>(ph_w1, ws + o_ph, nullptr, 0, ws + o_p1, nullptr,
                                      256, DD, 32);
    k_matvec<<<256, 256, 0, stream>>>(ph_w2, ws + o_p1, ph_b1, 1, ws + o_comb + 2048, ph_b2,
                                      256, 1024, 4);

    // entanglement path, grid-parallel:
    // 91 features (one block each) -> ef @ ent_w1(91x512) -> relu(+b1) @ ent_w2(512x512) + b2
    k_efeat<<<91, 256, 0, stream>>>(ws + o_x, ws + o_ef);
    k_matvec<<<4, 128, 0, stream>>>(ent_w1, ws + o_ef, nullptr, 0, ws + o_eh1, nullptr,
                                    128, 91, 23);
    k_matvec<<<16, 128, 0, stream>>>(ent_w2, ws + o_eh1, ent_b1, 1, ws + o_comb + 3072, ent_b2,
                                     128, 512, 32);

    // fusion: combined(3584) @ fus_w(3584x2048) + fus_b -> out
    k_matvec<<<256, 512, 0, stream>>>(fus_w, ws + o_comb, nullptr, 0, out, fus_b,
                                      512, 3584, 14);
}